// Round 12
// baseline (1062.667 us; speedup 1.0000x reference)
//
#include <hip/hip_runtime.h>
#include <hip/hip_fp16.h>
#include <math.h>
#include <stdio.h>

// N=50000, E=800000, IN=128, C=64, H=8, H*C=512
// R11: GEMM main loop -> NO LDS, NO barriers. Evidence: 145us across SIX
// interventions (4 schedules, write-cut, occupancy 1.5x) with MFMA 31% /
// VALU 18% / HBM 15% — stall invisible to counters; the one shared feature
// was LDS staging + 2 barriers/step (wave convoying). Now each wave loads
// its MFMA fragments DIRECTLY from L2-resident global (B=2MB weights;
// A panel L2-local via n-sweep block order) into registers, 1-step
// lookahead, compiler schedules its own counted waitcnts. ~2x L2 read
// amplification (14 -> ~28 TB/s needed, < 34.5 peak) is the known risk:
// if dur RISES, GEMM is L2-request-bound -> revert to R11-state and stop.
// k-chunk-per-quad order identical to swizzled-LDS path -> bitwise-same acc.
// Epilogue (LDS-staged stores), attn fp8 Q/KV, CSR: unchanged.

using f16x8 = __attribute__((ext_vector_type(8))) _Float16;
using f32x4 = __attribute__((ext_vector_type(4))) float;

// ---- fp8 e4m3 helpers (HW cvt on gfx950; software fallback kept for safety) ----
__device__ __forceinline__ void fp8x4_to_f32(unsigned int w, float* o4) {
#if __has_builtin(__builtin_amdgcn_cvt_pk_f32_fp8)
  auto lo = __builtin_amdgcn_cvt_pk_f32_fp8(w, false);
  auto hi = __builtin_amdgcn_cvt_pk_f32_fp8(w, true);
  o4[0] = lo[0]; o4[1] = lo[1]; o4[2] = hi[0]; o4[3] = hi[1];
#else
#pragma unroll
  for (int t = 0; t < 4; ++t) {
    unsigned int b = (w >> (8 * t)) & 0xFFu;
    unsigned short h = (unsigned short)(((b & 0x80u) << 8) | ((b & 0x7Fu) << 7));
    __half hv = *(__half*)&h;
    o4[t] = (float)hv * 256.0f;
  }
#endif
}

__device__ __forceinline__ unsigned int fp8_pack2_sw(float a, float b) {
  unsigned int r = 0;
#pragma unroll
  for (int t = 0; t < 2; ++t) {
    float f = t ? b : a;
    __half h = __float2half(f * (1.0f / 256.0f));
    unsigned short hb = *(unsigned short*)&h;
    unsigned int sign = (hb >> 8) & 0x80u;
    unsigned int mag = (hb & 0x7FFFu) + 0x40u;  // round
    unsigned int e = (mag >> 7) & 0x7Fu;
    if ((mag >> 7) > 0x7Eu) e = 0x7Eu;          // clamp below NaN pattern
    r |= (sign | e) << (8 * t);
  }
  return r;
}

__device__ __forceinline__ uint2 fp8_pack8(const float* f) {
#if __has_builtin(__builtin_amdgcn_cvt_pk_fp8_f32)
  int w0 = __builtin_amdgcn_cvt_pk_fp8_f32(f[0], f[1], 0, false);
  w0 = __builtin_amdgcn_cvt_pk_fp8_f32(f[2], f[3], w0, true);
  int w1 = __builtin_amdgcn_cvt_pk_fp8_f32(f[4], f[5], 0, false);
  w1 = __builtin_amdgcn_cvt_pk_fp8_f32(f[6], f[7], w1, true);
  uint2 r; r.x = (unsigned)w0; r.y = (unsigned)w1; return r;
#else
  uint2 r;
  r.x = fp8_pack2_sw(f[0], f[1]) | (fp8_pack2_sw(f[2], f[3]) << 16);
  r.y = fp8_pack2_sw(f[4], f[5]) | (fp8_pack2_sw(f[6], f[7]) << 16);
  return r;
#endif
}

// ---------------- prep: zero deg, zero H pad, convert x->fp16 ----------------
__global__ void prep_x_kernel(const float* __restrict__ x, __half* __restrict__ xh,
                              int* __restrict__ deg, __half* __restrict__ H,
                              int N, int Npad) {
  int t = blockIdx.x * 256 + threadIdx.x;
  if (t < N) deg[t] = 0;
  int nz = (Npad - N) * 64;  // pad vec8 slots of H
  if (t < nz) {
    f16x8 z = {};
    *(f16x8*)(H + (size_t)N * 512 + (size_t)t * 8) = z;
  }
  if (t < Npad * 16) {
    int row = t >> 4;
    f16x8 hv = {};
    if (row < N) {
      const float* g = x + (size_t)t * 8;
      float4 f0 = *(const float4*)g;
      float4 f1 = *(const float4*)(g + 4);
      hv[0] = (_Float16)f0.x; hv[1] = (_Float16)f0.y;
      hv[2] = (_Float16)f0.z; hv[3] = (_Float16)f0.w;
      hv[4] = (_Float16)f1.x; hv[5] = (_Float16)f1.y;
      hv[6] = (_Float16)f1.z; hv[7] = (_Float16)f1.w;
    }
    *(f16x8*)(xh + (size_t)t * 8) = hv;
  }
}

// ---------------- CSR build ----------------
__global__ void degree_kernel(const int* __restrict__ dst, int* __restrict__ deg, int E) {
  int e = blockIdx.x * blockDim.x + threadIdx.x;
  if (e < E) atomicAdd(&deg[dst[e]], 1);
}

__global__ __launch_bounds__(256)
void scan_a_kernel(const int* __restrict__ deg, int* __restrict__ rowptr,
                   int* __restrict__ bsum, int n) {
  __shared__ int tmp[256];
  int t = threadIdx.x;
  int i = blockIdx.x * 256 + t;
  int v = (i < n) ? deg[i] : 0;
  tmp[t] = v;
  __syncthreads();
#pragma unroll
  for (int off = 1; off < 256; off <<= 1) {
    int u = (t >= off) ? tmp[t - off] : 0;
    __syncthreads();
    tmp[t] += u;
    __syncthreads();
  }
  if (i < n) rowptr[i + 1] = tmp[t];
  if (t == 255) bsum[blockIdx.x] = tmp[255];
}

__global__ __launch_bounds__(256)
void scan_b_kernel(int* __restrict__ bsum, int nb) {
  __shared__ int tmp[256];
  int t = threadIdx.x;
  int v = (t < nb) ? bsum[t] : 0;
  tmp[t] = v;
  __syncthreads();
#pragma unroll
  for (int off = 1; off < 256; off <<= 1) {
    int u = (t >= off) ? tmp[t - off] : 0;
    __syncthreads();
    tmp[t] += u;
    __syncthreads();
  }
  if (t < nb) bsum[t] = tmp[t] - v;  // exclusive
}

__global__ __launch_bounds__(256)
void scan_c_kernel(int* __restrict__ rowptr, int* __restrict__ cursor,
                   const int* __restrict__ bsum, int n) {
  int i = blockIdx.x * 256 + threadIdx.x;
  if (i < n) {
    int r = rowptr[i + 1] + bsum[blockIdx.x];
    rowptr[i + 1] = r;
    cursor[i + 1] = r;
  }
  if (i == 0) { rowptr[0] = 0; cursor[0] = 0; }
}

__global__ void scatter_kernel(const int* __restrict__ src, const int* __restrict__ dst,
                               int* __restrict__ cursor, int* __restrict__ col, int E) {
  int e = blockIdx.x * blockDim.x + threadIdx.x;
  if (e < E) {
    int pos = atomicAdd(&cursor[dst[e]], 1);
    col[pos] = src[e];
  }
}

// ---------------- prep: weights/biases ----------------
__global__ __launch_bounds__(256)
void transpose_all_kernel(
    const float* __restrict__ Wq0, const float* __restrict__ Wk0,
    const float* __restrict__ Wv0, const float* __restrict__ Ws0,
    const float* __restrict__ Wq1, const float* __restrict__ Wk1,
    const float* __restrict__ Wv1, const float* __restrict__ Ws1,
    const float* __restrict__ Wq2, const float* __restrict__ Wk2,
    const float* __restrict__ Wv2, const float* __restrict__ Ws2,
    __half* __restrict__ Wt) {
  int z = blockIdx.z;
  int layer = z >> 2, m = z & 3;
  int K = (layer == 0) ? 128 : 512;
  int D = (layer == 2) ? 64 : 512;
  int c0 = blockIdx.x * 32, k0 = blockIdx.y * 32;
  if (c0 >= D || k0 >= K) return;
  const float* W;
  switch (z) {
    case 0: W = Wq0; break; case 1: W = Wk0; break;
    case 2: W = Wv0; break; case 3: W = Ws0; break;
    case 4: W = Wq1; break; case 5: W = Wk1; break;
    case 6: W = Wv1; break; case 7: W = Ws1; break;
    case 8: W = Wq2; break; case 9: W = Wk2; break;
    case 10: W = Wv2; break; default: W = Ws2; break;
  }
  __half* dstBase = Wt + ((layer == 0) ? 0 : (layer == 1) ? 262144 : 1310720);
  __shared__ float t[32][33];
  int tx = threadIdx.x & 31, ty = threadIdx.x >> 5;  // (32,8)
#pragma unroll
  for (int r = 0; r < 4; ++r)
    t[ty + 8 * r][tx] = W[(size_t)(k0 + ty + 8 * r) * D + c0 + tx];
  __syncthreads();
#pragma unroll
  for (int r = 0; r < 4; ++r)
    dstBase[(size_t)(m * D + c0 + ty + 8 * r) * K + k0 + tx] =
        __float2half(t[tx][ty + 8 * r]);
}

__global__ void bias_all_kernel(
    const float* __restrict__ b0, const float* __restrict__ b1,
    const float* __restrict__ b2, const float* __restrict__ b3,
    const float* __restrict__ b4, const float* __restrict__ b5,
    const float* __restrict__ b6, const float* __restrict__ b7,
    const float* __restrict__ b8, const float* __restrict__ b9,
    const float* __restrict__ b10, const float* __restrict__ b11,
    float* __restrict__ bias_arena) {
  int z = blockIdx.x;
  int layer = z >> 2, m = z & 3;
  int D = (layer == 2) ? 64 : 512;
  const float* b;
  switch (z) {
    case 0: b = b0; break; case 1: b = b1; break;
    case 2: b = b2; break; case 3: b = b3; break;
    case 4: b = b4; break; case 5: b = b5; break;
    case 6: b = b6; break; case 7: b = b7; break;
    case 8: b = b8; break; case 9: b = b9; break;
    case 10: b = b10; break; default: b = b11; break;
  }
  float* dst = bias_arena + ((layer == 0) ? 0 : (layer == 1) ? 2048 : 4096) + m * D;
  for (int c = threadIdx.x; c < D; c += 256) dst[c] = b[c];
}

// ---------------- MFMA GEMM: 128x128 block tile, 64x64 wave tile ----------------
// NO LDS / NO barriers in main loop: each wave loads its MFMA fragments
// directly from L2-resident global into registers (1-step lookahead;
// compiler inserts its own counted waitcnts). BK=32, k-chunk per quad —
// identical accumulation order to the LDS-swizzled path.
// Epilogue: LDS-staged coalesced stores (unchanged, own syncs).
template <int LAYER>
__global__ __launch_bounds__(256, 2)
void gemm_mfma_kernel(const __half* __restrict__ Aptr,
                      const __half* __restrict__ Wt,
                      const float* __restrict__ bias,
                      __half* __restrict__ QS, __half* __restrict__ KV,
                      unsigned char* __restrict__ Q8,
                      __half* __restrict__ S16) {
  constexpr int K = (LAYER == 0) ? 128 : 512;
  constexpr int lda = (LAYER == 0) ? 128 : 512;
  constexpr int NT = (LAYER == 2) ? 2 : 16;  // 128-wide n-tiles
  constexpr int NSTEP = K / 32;
  __shared__ __align__(16) char smem_raw[18432];  // epilogue staging only
  int tid = threadIdx.x;
  int wave = tid >> 6, lane = tid & 63;
  int wr = wave >> 1, wc = wave & 1;
  int bid = blockIdx.x;
  int xcd = bid & 7;
  int r = bid >> 3;
  int n0 = (r % NT) * 128;
  int m0 = ((r / NT) * 8 + xcd) * 128;
  // fragment decomposition: lane = quad*16 + rr
  int quad = lane >> 4, rr = lane & 15;

  // per-lane fragment base pointers (k advances by +kt)
  const __half* Abase = Aptr + (size_t)(m0 + wr * 64 + rr) * lda + quad * 8;
  const __half* Bbase = Wt + (size_t)(n0 + wc * 64 + rr) * K + quad * 8;

  f32x4 acc[4][4] = {};
  f16x8 a[4], b[4], an[4], bn[4];

#pragma unroll
  for (int i = 0; i < 4; ++i) {
    a[i] = *(const f16x8*)(Abase + (size_t)(i * 16) * lda);
    b[i] = *(const f16x8*)(Bbase + (size_t)(i * 16) * K);
  }

#pragma unroll
  for (int t = 0; t < NSTEP; ++t) {
    if (t + 1 < NSTEP) {
      int kn = (t + 1) * 32;
#pragma unroll
      for (int i = 0; i < 4; ++i) {
        an[i] = *(const f16x8*)(Abase + (size_t)(i * 16) * lda + kn);
        bn[i] = *(const f16x8*)(Bbase + (size_t)(i * 16) * K + kn);
      }
    }
#pragma unroll
    for (int i = 0; i < 4; ++i)
#pragma unroll
      for (int j = 0; j < 4; ++j)
        acc[i][j] = __builtin_amdgcn_mfma_f32_16x16x32_f16(a[i], b[j], acc[i][j], 0, 0, 0);
#pragma unroll
    for (int i = 0; i < 4; ++i) { a[i] = an[i]; b[i] = bn[i]; }
  }
  __syncthreads();  // align waves before epilogue smem staging

  // ---- epilogue: LDS-staged coalesced stores (BN=128) ----
  int cl = lane & 15, rb = (lane >> 4) * 4;

  if constexpr (LAYER == 2) {
    // fp16; 2 rounds of 64 rows; per-chunk seg routing (2 segs per block)
    __half* S = (__half*)smem_raw;  // [64][136] halves
#pragma unroll
    for (int round = 0; round < 2; ++round) {
      if (wr == round) {
#pragma unroll
        for (int i = 0; i < 4; ++i)
#pragma unroll
          for (int j = 0; j < 4; ++j) {
            int colL = wc * 64 + j * 16 + cl;
            float bj = bias[n0 + colL];
#pragma unroll
            for (int rg = 0; rg < 4; ++rg) {
              int rowL = i * 16 + rb + rg;
              S[rowL * 136 + colL] = __float2half(acc[i][j][rg] + bj);
            }
          }
      }
      __syncthreads();
#pragma unroll
      for (int it = 0; it < 4; ++it) {
        int id = it * 256 + tid;
        int rowL = id >> 4, ch = id & 15;
        int grow = m0 + round * 64 + rowL;
        int gcol = n0 + ch * 8;
        int seg = gcol >> 6, c = gcol & 63;
        __half* base = (seg == 0) ? QS + (size_t)grow * 128 + c
                     : (seg == 3) ? QS + (size_t)grow * 128 + 64 + c
                     : (seg == 1) ? KV + (size_t)grow * 128 + c
                                  : KV + (size_t)grow * 128 + 64 + c;
        *(f16x8*)base = *(const f16x8*)&S[rowL * 136 + ch * 8];
      }
      __syncthreads();
    }
  } else {
    const int msegB = n0 >> 9;   // block-uniform mseg (0=Q,1=K,2=V,3=S)
    const int cb = n0 & 511;     // col base within the 512-wide matrix
    if (msegB == 3) {
      // fp16 path -> S16 (512-half rows)
      __half* S = (__half*)smem_raw;  // [64][136] halves
#pragma unroll
      for (int round = 0; round < 2; ++round) {
        if (wr == round) {
#pragma unroll
          for (int i = 0; i < 4; ++i)
#pragma unroll
            for (int j = 0; j < 4; ++j) {
              int colL = wc * 64 + j * 16 + cl;
              float bj = bias[n0 + colL];
#pragma unroll
              for (int rg = 0; rg < 4; ++rg) {
                int rowL = i * 16 + rb + rg;
                S[rowL * 136 + colL] = __float2half(acc[i][j][rg] + bj);
              }
            }
        }
        __syncthreads();
#pragma unroll
        for (int it = 0; it < 4; ++it) {
          int id = it * 256 + tid;
          int rowL = id >> 4, ch = id & 15;
          int grow = m0 + round * 64 + rowL;
          int colb = ch * 8;
          *(f16x8*)(S16 + (size_t)grow * 512 + cb + colb) =
              *(const f16x8*)&S[rowL * 136 + colb];
        }
        __syncthreads();
      }
    } else if (msegB == 0) {
      // fp8 dense path -> Q8 (512-byte rows)
      float* S = (float*)smem_raw;  // [32][132] floats
#pragma unroll
      for (int round = 0; round < 4; ++round) {
        if (wr == (round >> 1)) {
#pragma unroll
          for (int ii = 0; ii < 2; ++ii) {
#pragma unroll
            for (int j = 0; j < 4; ++j) {
              int colL = wc * 64 + j * 16 + cl;
              float bj = bias[n0 + colL];
#pragma unroll
              for (int rg = 0; rg < 4; ++rg) {
                int rowL = ii * 16 + rb + rg;
                S[rowL * 132 + colL] = acc[(round & 1) * 2 + ii][j][rg] + bj;
              }
            }
          }
        }
        __syncthreads();
#pragma unroll
        for (int it = 0; it < 2; ++it) {
          int id = it * 256 + tid;
          int rowL = id >> 4, ch = id & 15;
          int grow = m0 + round * 32 + rowL;
          int colb = ch * 8;
          float f[8];
          f32x4 lo = *(const f32x4*)&S[rowL * 132 + colb];
          f32x4 hi = *(const f32x4*)&S[rowL * 132 + colb + 4];
          f[0] = lo[0]; f[1] = lo[1]; f[2] = lo[2]; f[3] = lo[3];
          f[4] = hi[0]; f[5] = hi[1]; f[6] = hi[2]; f[7] = hi[3];
          uint2 pk = fp8_pack8(f);
          *(uint2*)(Q8 + (size_t)grow * 512 + cb + colb) = pk;
        }
        __syncthreads();
      }
    } else {
      // fp8 path -> KV8 interleaved [K 8B | V 8B] per 8-col group (1KB rows)
      float* S = (float*)smem_raw;  // [32][132] floats
      unsigned char* KV8 = (unsigned char*)KV;
      const int koff = (msegB == 2) ? 8 : 0;
#pragma unroll
      for (int round = 0; round < 4; ++round) {
        if (wr == (round >> 1)) {
#pragma unroll
          for (int ii = 0; ii < 2; ++ii) {
#pragma unroll
            for (int j = 0; j < 4; ++j) {
              int colL = wc * 64 + j * 16 + cl;
              float bj = bias[n0 + colL];
#pragma unroll
              for (int rg = 0; rg < 4; ++rg) {
                int rowL = ii * 16 + rb + rg;
                S[rowL * 132 + colL] = acc[(round & 1) * 2 + ii][j][rg] + bj;
              }
            }
          }
        }
        __syncthreads();
#pragma unroll
        for (int it = 0; it < 2; ++it) {
          int id = it * 256 + tid;
          int rowL = id >> 4, ch = id & 15;
          int grow = m0 + round * 32 + rowL;
          int colb = ch * 8;
          float f[8];
          f32x4 lo = *(const f32x4*)&S[rowL * 132 + colb];
          f32x4 hi = *(const f32x4*)&S[rowL * 132 + colb + 4];
          f[0] = lo[0]; f[1] = lo[1]; f[2] = lo[2]; f[3] = lo[3];
          f[4] = hi[0]; f[5] = hi[1]; f[6] = hi[2]; f[7] = hi[3];
          uint2 pk = fp8_pack8(f);
          *(uint2*)(KV8 + (size_t)grow * 1024 + ((cb + colb) >> 3) * 16 + koff) = pk;
        }
        __syncthreads();
      }
    }
  }
}

// ---------------- attention H=8 C=64: one WAVE per node, fp8 Q/KV ----------------
__global__ __launch_bounds__(256)
void attn_h8_kernel(const unsigned char* __restrict__ Q8,
                    const __half* __restrict__ S16,
                    const unsigned char* __restrict__ KV8,
                    const int* __restrict__ rowptr, const int* __restrict__ col,
                    __half* __restrict__ Hout, int N) {
  int n = blockIdx.x * 4 + (threadIdx.x >> 6);
  if (n >= N) return;
  int lane = threadIdx.x & 63;

  uint2 qw = *(const uint2*)(Q8 + (size_t)n * 512 + lane * 8);
  float qf[8];
  fp8x4_to_f32(qw.x, qf);
  fp8x4_to_f32(qw.y, qf + 4);

  int e0 = rowptr[n], e1 = rowptr[n + 1];
  float m = -INFINITY, l = 0.f;
  float o[8] = {};

  const uint4* KVL = (const uint4*)KV8;  // one row = 64 uint4 (lane-interleaved K|V)
  uint4 ea = {}, eb = {};
  int i = e0;
  if (i < e1)     ea = KVL[(size_t)col[i] * 64 + lane];
  if (i + 1 < e1) eb = KVL[(size_t)col[i + 1] * 64 + lane];

  while (i < e1) {
    int rem = e1 - i;
    uint4 ec = {}, ed = {};
    if (rem > 2) ec = KVL[(size_t)col[i + 2] * 64 + lane];
    if (rem > 3) ed = KVL[(size_t)col[i + 3] * 64 + lane];
    float ka[8], kb[8];
    fp8x4_to_f32(ea.x, ka); fp8x4_to_f32(ea.y, ka + 4);
    fp8x4_to_f32(eb.x, kb); fp8x4_to_f32(eb.y, kb + 4);
    float pa = 0.f, pb = 0.f;
#pragma unroll
    for (int j = 0; j < 8; ++j) { pa += ka[j] * qf[j]; pb += kb[j] * qf[j]; }
    pa += __shfl_xor(pa, 1, 64); pb += __shfl_xor(pb, 1, 64);
    pa += __shfl_xor(pa, 2, 64); pb += __shfl_xor(pb, 2, 64);
    pa += __shfl_xor(pa, 4, 64); pb += __shfl_xor(pb, 4, 64);
    float a0 = pa * 0.125f;
    float va[8];
    fp8x4_to_f32(ea.z, va); fp8x4_to_f32(ea.w, va + 4);
    if (rem > 1) {
      float vb[8];
      fp8x4_to_f32(eb.z, vb); fp8x4_to_f32(eb.w, vb + 4);
      float a1 = pb * 0.125f;
      float mn = fmaxf(m, fmaxf(a0, a1));
      float sc = __expf(m - mn);
      float ex0 = __expf(a0 - mn), ex1 = __expf(a1 - mn);
      l = l * sc + ex0 + ex1;
#pragma unroll
      for (int c = 0; c < 8; ++c)
        o[c] = o[c] * sc + ex0 * va[c] + ex1 * vb[c];
      m = mn;
    } else {
      float mn = fmaxf(m, a0);
      float sc = __expf(m - mn);
      float ex0 = __expf(a0 - mn);
      l = l * sc + ex0;
#pragma unroll
      for (int c = 0; c < 8; ++c) o[c] = o[c] * sc + ex0 * va[c];
      m = mn;
    }
    ea = ec; eb = ed;
    i += 2;
  }

  float inv = 1.f / (l + 1e-16f);
  f16x8 sv = __builtin_nontemporal_load((const f16x8*)(S16 + (size_t)n * 512 + lane * 8));
  f16x8 hv;
#pragma unroll
  for (int c = 0; c < 8; ++c) {
    float r = o[c] * inv + (float)sv[c];
    hv[c] = (_Float16)fmaxf(r, 0.f);
  }
  __builtin_nontemporal_store(hv, (f16x8*)(Hout + (size_t)n * 512 + lane * 8));
}

// ---------------- attention H=1 C=64: 8-lane group per node, fp16 KV ----------------
__global__ __launch_bounds__(256)
void attn_h1_kernel(const __half* __restrict__ QS, const __half* __restrict__ KV,
                    const int* __restrict__ rowptr, const int* __restrict__ col,
                    float* __restrict__ out, int N) {
  int n = (blockIdx.x * 256 + threadIdx.x) >> 3;
  if (n >= N) return;
  int gl = threadIdx.x & 7;
  size_t rbase = (size_t)n * 128 + gl * 8;

  f16x8 qv = __builtin_nontemporal_load((const f16x8*)(QS + rbase));
  float qf[8];
#pragma unroll
  for (int j = 0; j < 8; ++j) qf[j] = (float)qv[j];

  int e0 = rowptr[n], e1 = rowptr[n + 1];
  float m = -INFINITY, l = 0.f;
  float o[8] = {};

  f16x8 ka = {}, va = {}, kb = {}, vb = {};
  int i = e0;
  if (i < e1) {
    const __half* p = KV + (size_t)col[i] * 128 + gl * 8;
    ka = *(const f16x8*)p; va = *(const f16x8*)(p + 64);
  }
  if (i + 1 < e1) {
    const __half* p = KV + (size_t)col[i + 1] * 128 + gl * 8;
    kb = *(const f16x8*)p; vb = *(const f16x8*)(p + 64);
  }

  while (i < e1) {
    int rem = e1 - i;
    f16x8 kc = {}, vc = {}, kd = {}, vd = {};
    if (rem > 2) {
      const __half* p = KV + (size_t)col[i + 2] * 128 + gl * 8;
      kc = *(const f16x8*)p; vc = *(const f16x8*)(p + 64);
    }
    if (rem > 3) {
      const __half* p = KV + (size_t)col[i + 3] * 128 + gl * 8;
      kd = *(const f16x8*)p; vd = *(const f16x8*)(p + 64);
    }
    float pa = 0.f, pb = 0.f;
#pragma unroll
    for (int j = 0; j < 8; ++j) { pa += (float)ka[j] * qf[j]; pb += (float)kb[j] * qf[j]; }
    pa += __shfl_xor(pa, 1, 64); pb += __shfl_xor(pb, 1, 64);
    pa += __shfl_xor(pa, 2, 64); pb += __shfl_xor(pb, 2, 64);
    pa += __shfl_xor(pa, 4, 64); pb += __shfl_xor(pb, 4, 64);
    float a0 = pa * 0.125f;
    if (rem > 1) {
      float a1 = pb * 0.125f;
      float mn = fmaxf(m, fmaxf(a0, a1));
      float sc = __expf(m - mn);
      float ea = __expf(a0 - mn), eb = __expf(a1 - mn);
      l = l * sc + ea + eb;
#pragma unroll
      for (int c = 0; c < 8; ++c)
        o[c] = o[c] * sc + ea * (float)va[c] + eb * (float)vb[c];
      m = mn;
    } else {
      float mn = fmaxf(m, a0);
      float sc = __expf(m - mn);
      float ea = __expf(a0 - mn);
      l = l * sc + ea;
#pragma unroll
      for (int c = 0; c < 8; ++c) o[c] = o[c] * sc + ea * (float)va[c];
      m = mn;
    }
    ka = kc; va = vc; kb = kd; vb = vd;
    i += 2;
  }

  float inv = 1.f / (l + 1e-16f);
  f16x8 sv = __builtin_nontemporal_load((const f16x8*)(QS + rbase + 64));
  f32x4 r0, r1;
#pragma unroll
  for (int c = 0; c < 4; ++c) r0[c] = o[c] * inv + (float)sv[c];
#pragma unroll
  for (int c = 0; c < 4; ++c) r1[c] = o[c + 4] * inv + (float)sv[c + 4];
  float* op = out + (size_t)n * 64 + gl * 8;
  *(f32x4*)op = r0;
  *(f32x4*)(op + 4) = r1;
}

extern "C" void kernel_launch(void* const* d_in, const int* in_sizes, int n_in,
                              void* d_out, int out_size, void* d_ws, size_t ws_size,
                              hipStream_t stream) {
  const float* x = (const float*)d_in[0];
  const int* ei = (const int*)d_in[1];
  const int N = in_sizes[0] / 128;
  const int E = in_sizes[1] / 2;
  // pad M so mtiles is a multiple of 8 (XCD striping)
  const int Npad = ((N + 1023) / 1024) * 1024;
  const int mtiles = Npad / 128;
  const int* srcp = ei;
  const int* dstp = ei + E;

  const float* Wq0 = (const float*)d_in[2];  const float* bq0 = (const float*)d_in[3];
  const float* Wk0 = (const float*)d_in[4];  const float* bk0 = (const float*)d_in[5];
  const float* Wv0 = (const float*)d_in[6];  const float* bv0 = (const float*)d_in[7];
  const float* Ws0 = (const float*)d_in[8];  const float* bs0 = (const float*)d_in[9];
  const float* Wq1 = (const float*)d_in[10]; const float* bq1 = (const float*)d_in[11];
  const float* Wk1 = (const float*)d_in[12]; const float* bk1 = (const float*)d_in[13];
  const float* Wv1 = (const float*)d_in[14]; const float* bv1 = (const float*)d_in[15];
  const float* Ws1 = (const float*)d_in[16]; const float* bs1 = (const float*)d_in[17];
  const float* Wq2 = (const float*)d_in[18]; const float* bq2 = (const float*)d_in[19];
  const float* Wk2 = (const float*)d_in[20]; const float* bk2 = (const float*)d_in[21];
  const float* Wv2 = (const float*)d_in[22]; const float* bv2 = (const float*)d_in[23];
  const float* Ws2 = (const float*)d_in[24]; const float* bs2 = (const float*)d_in[25];

  // ---- workspace layout ----
  char* p = (char*)d_ws;
  __half* S16 = (__half*)p;              p += (size_t)Npad * 512 * 2;   // 51.4 MB (S; layer2 reuses as QS 128-half rows)
  unsigned char* Q8 = (unsigned char*)p; p += (size_t)Npad * 512;       // 25.7 MB
  __half* KV = (__half*)p;               p += (size_t)Npad * 1024;      // fp8 1KB rows; layer2 fp16 256B rows
  __half* H  = (__half*)p;               p += (size_t)Npad * 512 * 2;   // 51.4 MB
  __half* xh = (__half*)p;               p += (size_t)Npad * 128 * 2;   // 12.8 MB
  __half* Wt = (__half*)p;               p += (size_t)1441792 * 2;      // 2.88 MB
  float* bias_arena = (float*)p;         p += 4352 * 4;
  int* deg    = (int*)p;                 p += (size_t)N * 4;
  int* rowptr = (int*)p;                 p += (size_t)(N + 1) * 4;
  int* cursor = (int*)p;                 p += (size_t)(N + 1) * 4;
  int* colv   = (int*)p;                 p += (size_t)E * 4;
  int* bsum   = (int*)p;                 p += 256 * 4;
  size_t need = p - (char*)d_ws;
  if (ws_size < need) {
    fprintf(stderr, "kernel_launch: ws_size=%zu < need=%zu — aborting cleanly\n",
            ws_size, need);
    return;
  }

  const int nscan = (N + 255) / 256;

  // ---- prep ----
  transpose_all_kernel<<<dim3(16, 16, 12), 256, 0, stream>>>(
      Wq0, Wk0, Wv0, Ws0, Wq1, Wk1, Wv1, Ws1, Wq2, Wk2, Wv2, Ws2, Wt);
  bias_all_kernel<<<12, 256, 0, stream>>>(
      bq0, bk0, bv0, bs0, bq1, bk1, bv1, bs1, bq2, bk2, bv2, bs2, bias_arena);
  prep_x_kernel<<<(Npad * 16 + 255) / 256, 256, 0, stream>>>(x, xh, deg, H, N, Npad);

  // ---- CSR build ----
  degree_kernel<<<(E + 255) / 256, 256, 0, stream>>>(dstp, deg, E);
  scan_a_kernel<<<nscan, 256, 0, stream>>>(deg, rowptr, bsum, N);
  scan_b_kernel<<<1, 256, 0, stream>>>(bsum, nscan);
  scan_c_kernel<<<nscan, 256, 0, stream>>>(rowptr, cursor, bsum, N);
  scatter_kernel<<<(E + 255) / 256, 256, 0, stream>>>(srcp, dstp, cursor, colv, E);

  __half* Wt0 = Wt;
  __half* Wt1 = Wt + 262144;
  __half* Wt2 = Wt + 1310720;

  // ---- layer 0: K=128, D=2048 cols, n-tiles 16 ----
  gemm_mfma_kernel<0><<<mtiles * 16, 256, 0, stream>>>(
      xh, Wt0, bias_arena, S16, KV, Q8, S16);
  attn_h8_kernel<<<(N + 3) / 4, 256, 0, stream>>>(Q8, S16, (const unsigned char*)KV,
                                                  rowptr, colv, H, N);

  // ---- layer 1: K=512, D=2048 cols, n-tiles 16 ----
  gemm_mfma_kernel<1><<<mtiles * 16, 256, 0, stream>>>(
      H, Wt1, bias_arena + 2048, S16, KV, Q8, S16);
  attn_h8_kernel<<<(N + 3) / 4, 256, 0, stream>>>(Q8, S16, (const unsigned char*)KV,
                                                  rowptr, colv, H, N);

  // ---- layer 2: K=512, D=256 cols, n-tiles 2 (fp16 path, S16 reused as QS) ----
  gemm_mfma_kernel<2><<<mtiles * 2, 256, 0, stream>>>(
      H, Wt2, bias_arena + 4096, S16, KV, Q8, S16);
  attn_h1_kernel<<<(N + 31) / 32, 256, 0, stream>>>(S16, KV, rowptr, colv,
                                                    (float*)d_out, N);
}

// Round 13
// 703.603 us; speedup vs baseline: 1.5103x; 1.5103x over previous
//
#include <hip/hip_runtime.h>
#include <hip/hip_fp16.h>
#include <math.h>
#include <stdio.h>

// N=50000, E=800000, IN=128, C=64, H=8, H*C=512
// R12: PURE REVERT to the R10 best state (701.1us, absmax 0.0083).
// R11's no-LDS main loop was a decisive failure (422us, MfmaUtil 10%,
// L2-request storm from scattered per-lane fragment loads) — confirming
// the LDS-staged pipeline is the right structure and the GEMM is
// L2-latency bound at ~145us/31% for this shape (7 interventions pinned).
// GEMM: 128x128 tile, 3-deep LDS pipeline, counted vmcnt 8/4/0,
// launch_bounds(256,3), acc[4][4]. attn: fp8 Q/KV. CSR/prep unchanged.

using f16x8 = __attribute__((ext_vector_type(8))) _Float16;
using f32x4 = __attribute__((ext_vector_type(4))) float;

__device__ __forceinline__ void load_lds16(const void* g, void* l) {
  __builtin_amdgcn_global_load_lds((const __attribute__((address_space(1))) void*)g,
                                   (__attribute__((address_space(3))) void*)l,
                                   16, 0, 0);
}

// ---- fp8 e4m3 helpers (HW cvt on gfx950; software fallback kept for safety) ----
__device__ __forceinline__ void fp8x4_to_f32(unsigned int w, float* o4) {
#if __has_builtin(__builtin_amdgcn_cvt_pk_f32_fp8)
  auto lo = __builtin_amdgcn_cvt_pk_f32_fp8(w, false);
  auto hi = __builtin_amdgcn_cvt_pk_f32_fp8(w, true);
  o4[0] = lo[0]; o4[1] = lo[1]; o4[2] = hi[0]; o4[3] = hi[1];
#else
#pragma unroll
  for (int t = 0; t < 4; ++t) {
    unsigned int b = (w >> (8 * t)) & 0xFFu;
    unsigned short h = (unsigned short)(((b & 0x80u) << 8) | ((b & 0x7Fu) << 7));
    __half hv = *(__half*)&h;
    o4[t] = (float)hv * 256.0f;
  }
#endif
}

__device__ __forceinline__ unsigned int fp8_pack2_sw(float a, float b) {
  unsigned int r = 0;
#pragma unroll
  for (int t = 0; t < 2; ++t) {
    float f = t ? b : a;
    __half h = __float2half(f * (1.0f / 256.0f));
    unsigned short hb = *(unsigned short*)&h;
    unsigned int sign = (hb >> 8) & 0x80u;
    unsigned int mag = (hb & 0x7FFFu) + 0x40u;  // round
    unsigned int e = (mag >> 7) & 0x7Fu;
    if ((mag >> 7) > 0x7Eu) e = 0x7Eu;          // clamp below NaN pattern
    r |= (sign | e) << (8 * t);
  }
  return r;
}

__device__ __forceinline__ uint2 fp8_pack8(const float* f) {
#if __has_builtin(__builtin_amdgcn_cvt_pk_fp8_f32)
  int w0 = __builtin_amdgcn_cvt_pk_fp8_f32(f[0], f[1], 0, false);
  w0 = __builtin_amdgcn_cvt_pk_fp8_f32(f[2], f[3], w0, true);
  int w1 = __builtin_amdgcn_cvt_pk_fp8_f32(f[4], f[5], 0, false);
  w1 = __builtin_amdgcn_cvt_pk_fp8_f32(f[6], f[7], w1, true);
  uint2 r; r.x = (unsigned)w0; r.y = (unsigned)w1; return r;
#else
  uint2 r;
  r.x = fp8_pack2_sw(f[0], f[1]) | (fp8_pack2_sw(f[2], f[3]) << 16);
  r.y = fp8_pack2_sw(f[4], f[5]) | (fp8_pack2_sw(f[6], f[7]) << 16);
  return r;
#endif
}

// ---------------- prep: zero deg, zero H pad, convert x->fp16 ----------------
__global__ void prep_x_kernel(const float* __restrict__ x, __half* __restrict__ xh,
                              int* __restrict__ deg, __half* __restrict__ H,
                              int N, int Npad) {
  int t = blockIdx.x * 256 + threadIdx.x;
  if (t < N) deg[t] = 0;
  int nz = (Npad - N) * 64;  // pad vec8 slots of H
  if (t < nz) {
    f16x8 z = {};
    *(f16x8*)(H + (size_t)N * 512 + (size_t)t * 8) = z;
  }
  if (t < Npad * 16) {
    int row = t >> 4;
    f16x8 hv = {};
    if (row < N) {
      const float* g = x + (size_t)t * 8;
      float4 f0 = *(const float4*)g;
      float4 f1 = *(const float4*)(g + 4);
      hv[0] = (_Float16)f0.x; hv[1] = (_Float16)f0.y;
      hv[2] = (_Float16)f0.z; hv[3] = (_Float16)f0.w;
      hv[4] = (_Float16)f1.x; hv[5] = (_Float16)f1.y;
      hv[6] = (_Float16)f1.z; hv[7] = (_Float16)f1.w;
    }
    *(f16x8*)(xh + (size_t)t * 8) = hv;
  }
}

// ---------------- CSR build ----------------
__global__ void degree_kernel(const int* __restrict__ dst, int* __restrict__ deg, int E) {
  int e = blockIdx.x * blockDim.x + threadIdx.x;
  if (e < E) atomicAdd(&deg[dst[e]], 1);
}

__global__ __launch_bounds__(256)
void scan_a_kernel(const int* __restrict__ deg, int* __restrict__ rowptr,
                   int* __restrict__ bsum, int n) {
  __shared__ int tmp[256];
  int t = threadIdx.x;
  int i = blockIdx.x * 256 + t;
  int v = (i < n) ? deg[i] : 0;
  tmp[t] = v;
  __syncthreads();
#pragma unroll
  for (int off = 1; off < 256; off <<= 1) {
    int u = (t >= off) ? tmp[t - off] : 0;
    __syncthreads();
    tmp[t] += u;
    __syncthreads();
  }
  if (i < n) rowptr[i + 1] = tmp[t];
  if (t == 255) bsum[blockIdx.x] = tmp[255];
}

__global__ __launch_bounds__(256)
void scan_b_kernel(int* __restrict__ bsum, int nb) {
  __shared__ int tmp[256];
  int t = threadIdx.x;
  int v = (t < nb) ? bsum[t] : 0;
  tmp[t] = v;
  __syncthreads();
#pragma unroll
  for (int off = 1; off < 256; off <<= 1) {
    int u = (t >= off) ? tmp[t - off] : 0;
    __syncthreads();
    tmp[t] += u;
    __syncthreads();
  }
  if (t < nb) bsum[t] = tmp[t] - v;  // exclusive
}

__global__ __launch_bounds__(256)
void scan_c_kernel(int* __restrict__ rowptr, int* __restrict__ cursor,
                   const int* __restrict__ bsum, int n) {
  int i = blockIdx.x * 256 + threadIdx.x;
  if (i < n) {
    int r = rowptr[i + 1] + bsum[blockIdx.x];
    rowptr[i + 1] = r;
    cursor[i + 1] = r;
  }
  if (i == 0) { rowptr[0] = 0; cursor[0] = 0; }
}

__global__ void scatter_kernel(const int* __restrict__ src, const int* __restrict__ dst,
                               int* __restrict__ cursor, int* __restrict__ col, int E) {
  int e = blockIdx.x * blockDim.x + threadIdx.x;
  if (e < E) {
    int pos = atomicAdd(&cursor[dst[e]], 1);
    col[pos] = src[e];
  }
}

// ---------------- prep: weights/biases ----------------
__global__ __launch_bounds__(256)
void transpose_all_kernel(
    const float* __restrict__ Wq0, const float* __restrict__ Wk0,
    const float* __restrict__ Wv0, const float* __restrict__ Ws0,
    const float* __restrict__ Wq1, const float* __restrict__ Wk1,
    const float* __restrict__ Wv1, const float* __restrict__ Ws1,
    const float* __restrict__ Wq2, const float* __restrict__ Wk2,
    const float* __restrict__ Wv2, const float* __restrict__ Ws2,
    __half* __restrict__ Wt) {
  int z = blockIdx.z;
  int layer = z >> 2, m = z & 3;
  int K = (layer == 0) ? 128 : 512;
  int D = (layer == 2) ? 64 : 512;
  int c0 = blockIdx.x * 32, k0 = blockIdx.y * 32;
  if (c0 >= D || k0 >= K) return;
  const float* W;
  switch (z) {
    case 0: W = Wq0; break; case 1: W = Wk0; break;
    case 2: W = Wv0; break; case 3: W = Ws0; break;
    case 4: W = Wq1; break; case 5: W = Wk1; break;
    case 6: W = Wv1; break; case 7: W = Ws1; break;
    case 8: W = Wq2; break; case 9: W = Wk2; break;
    case 10: W = Wv2; break; default: W = Ws2; break;
  }
  __half* dstBase = Wt + ((layer == 0) ? 0 : (layer == 1) ? 262144 : 1310720);
  __shared__ float t[32][33];
  int tx = threadIdx.x & 31, ty = threadIdx.x >> 5;  // (32,8)
#pragma unroll
  for (int r = 0; r < 4; ++r)
    t[ty + 8 * r][tx] = W[(size_t)(k0 + ty + 8 * r) * D + c0 + tx];
  __syncthreads();
#pragma unroll
  for (int r = 0; r < 4; ++r)
    dstBase[(size_t)(m * D + c0 + ty + 8 * r) * K + k0 + tx] =
        __float2half(t[tx][ty + 8 * r]);
}

__global__ void bias_all_kernel(
    const float* __restrict__ b0, const float* __restrict__ b1,
    const float* __restrict__ b2, const float* __restrict__ b3,
    const float* __restrict__ b4, const float* __restrict__ b5,
    const float* __restrict__ b6, const float* __restrict__ b7,
    const float* __restrict__ b8, const float* __restrict__ b9,
    const float* __restrict__ b10, const float* __restrict__ b11,
    float* __restrict__ bias_arena) {
  int z = blockIdx.x;
  int layer = z >> 2, m = z & 3;
  int D = (layer == 2) ? 64 : 512;
  const float* b;
  switch (z) {
    case 0: b = b0; break; case 1: b = b1; break;
    case 2: b = b2; break; case 3: b = b3; break;
    case 4: b = b4; break; case 5: b = b5; break;
    case 6: b = b6; break; case 7: b = b7; break;
    case 8: b = b8; break; case 9: b = b9; break;
    case 10: b = b10; break; default: b = b11; break;
  }
  float* dst = bias_arena + ((layer == 0) ? 0 : (layer == 1) ? 2048 : 4096) + m * D;
  for (int c = threadIdx.x; c < D; c += 256) dst[c] = b[c];
}

// ---------------- MFMA GEMM: 128x128 block tile, 64x64 wave tile ----------------
// BK=32, 3-deep LDS pipeline (3 x 16KB = 48KB -> 3 blocks/CU). Counted vmcnt:
// 4 loads/thread/step, waits 8/4/0. acc[4][4] = 64 VGPR -> (256,3) safe.
// Epilogue: LDS-staged coalesced stores for BN=128.
template <int LAYER>
__global__ __launch_bounds__(256, 3)
void gemm_mfma_kernel(const __half* __restrict__ Aptr,
                      const __half* __restrict__ Wt,
                      const float* __restrict__ bias,
                      __half* __restrict__ QS, __half* __restrict__ KV,
                      unsigned char* __restrict__ Q8,
                      __half* __restrict__ S16) {
  constexpr int K = (LAYER == 0) ? 128 : 512;
  constexpr int lda = (LAYER == 0) ? 128 : 512;
  constexpr int NT = (LAYER == 2) ? 2 : 16;  // 128-wide n-tiles
  constexpr int NSTEP = K / 32;
  __shared__ __align__(16) char smem_raw[49152];  // 3 x 16KB
  __half* sm = (__half*)smem_raw;
  int tid = threadIdx.x;
  int wave = tid >> 6, lane = tid & 63;
  int wr = wave >> 1, wc = wave & 1;
  int bid = blockIdx.x;
  int xcd = bid & 7;
  int r = bid >> 3;
  int n0 = (r % NT) * 128;
  int m0 = ((r / NT) * 8 + xcd) * 128;
  // staging decomposition: lane -> (row-in-16, slot-in-4)
  int srow = lane >> 2;
  int sslot = lane & 3;
  int skc = (sslot ^ ((srow >> 1) & 3)) << 3;  // swizzled k offset (halves)
  // fragment read decomposition
  int quad = lane >> 4, rr = lane & 15;
  int rslot = (quad ^ ((rr >> 1) & 3)) << 3;   // read k offset within row

  f32x4 acc[4][4] = {};

  auto stage = [&](int buf, int kt) {
    __half* As = sm + buf * 8192;   // 16KB buffer: A 4096 halves + B 4096
    __half* Bs = As + 4096;
#pragma unroll
    for (int p = 0; p < 2; ++p) {
      int rbase = wave * 32 + p * 16;
      const __half* ga = Aptr + (size_t)(m0 + rbase + srow) * lda + kt + skc;
      load_lds16(ga, &As[rbase * 32]);
    }
#pragma unroll
    for (int p = 0; p < 2; ++p) {
      int rbase = wave * 32 + p * 16;
      const __half* gb = Wt + (size_t)(n0 + rbase + srow) * K + kt + skc;
      load_lds16(gb, &Bs[rbase * 32]);
    }
  };

  // prologue: 3 tiles in flight (NSTEP >= 4 for all layers)
  stage(0, 0);
  stage(1, 32);
  stage(2, 64);

  for (int t = 0; t < NSTEP; ++t) {
    if (t + 2 < NSTEP)      asm volatile("s_waitcnt vmcnt(8)" ::: "memory");
    else if (t + 1 < NSTEP) asm volatile("s_waitcnt vmcnt(4)" ::: "memory");
    else                    asm volatile("s_waitcnt vmcnt(0)" ::: "memory");
    __builtin_amdgcn_s_barrier();  // all waves' tile-t loads landed

    const __half* As = sm + (t % 3) * 8192;
    const __half* Bs = As + 4096;
    f16x8 a[4], b[4];
#pragma unroll
    for (int i = 0; i < 4; ++i) {
      int row = wr * 64 + i * 16 + rr;
      a[i] = *(const f16x8*)&As[row * 32 + rslot];
    }
#pragma unroll
    for (int j = 0; j < 4; ++j) {
      int row = wc * 64 + j * 16 + rr;
      b[j] = *(const f16x8*)&Bs[row * 32 + rslot];
    }
    __builtin_amdgcn_s_setprio(1);
#pragma unroll
    for (int i = 0; i < 4; ++i)
#pragma unroll
      for (int j = 0; j < 4; ++j)
        acc[i][j] = __builtin_amdgcn_mfma_f32_16x16x32_f16(a[i], b[j], acc[i][j], 0, 0, 0);
    __builtin_amdgcn_s_setprio(0);
    __builtin_amdgcn_s_barrier();  // reads of buf t%3 all consumed
    if (t + 3 < NSTEP) stage(t % 3, (t + 3) * 32);
  }
  __syncthreads();  // protect epilogue's smem reuse

  // ---- epilogue: LDS-staged coalesced stores (BN=128) ----
  int cl = lane & 15, rb = (lane >> 4) * 4;

  if constexpr (LAYER == 2) {
    // fp16; 2 rounds of 64 rows; per-chunk seg routing (2 segs per block)
    __half* S = (__half*)smem_raw;  // [64][136] halves
#pragma unroll
    for (int round = 0; round < 2; ++round) {
      if (wr == round) {
#pragma unroll
        for (int i = 0; i < 4; ++i)
#pragma unroll
          for (int j = 0; j < 4; ++j) {
            int colL = wc * 64 + j * 16 + cl;
            float bj = bias[n0 + colL];
#pragma unroll
            for (int rg = 0; rg < 4; ++rg) {
              int rowL = i * 16 + rb + rg;
              S[rowL * 136 + colL] = __float2half(acc[i][j][rg] + bj);
            }
          }
      }
      __syncthreads();
#pragma unroll
      for (int it = 0; it < 4; ++it) {
        int id = it * 256 + tid;
        int rowL = id >> 4, ch = id & 15;
        int grow = m0 + round * 64 + rowL;
        int gcol = n0 + ch * 8;
        int seg = gcol >> 6, c = gcol & 63;
        __half* base = (seg == 0) ? QS + (size_t)grow * 128 + c
                     : (seg == 3) ? QS + (size_t)grow * 128 + 64 + c
                     : (seg == 1) ? KV + (size_t)grow * 128 + c
                                  : KV + (size_t)grow * 128 + 64 + c;
        *(f16x8*)base = *(const f16x8*)&S[rowL * 136 + ch * 8];
      }
      __syncthreads();
    }
  } else {
    const int msegB = n0 >> 9;   // block-uniform mseg (0=Q,1=K,2=V,3=S)
    const int cb = n0 & 511;     // col base within the 512-wide matrix
    if (msegB == 3) {
      // fp16 path -> S16 (512-half rows)
      __half* S = (__half*)smem_raw;  // [64][136] halves
#pragma unroll
      for (int round = 0; round < 2; ++round) {
        if (wr == round) {
#pragma unroll
          for (int i = 0; i < 4; ++i)
#pragma unroll
            for (int j = 0; j < 4; ++j) {
              int colL = wc * 64 + j * 16 + cl;
              float bj = bias[n0 + colL];
#pragma unroll
              for (int rg = 0; rg < 4; ++rg) {
                int rowL = i * 16 + rb + rg;
                S[rowL * 136 + colL] = __float2half(acc[i][j][rg] + bj);
              }
            }
        }
        __syncthreads();
#pragma unroll
        for (int it = 0; it < 4; ++it) {
          int id = it * 256 + tid;
          int rowL = id >> 4, ch = id & 15;
          int grow = m0 + round * 64 + rowL;
          int colb = ch * 8;
          *(f16x8*)(S16 + (size_t)grow * 512 + cb + colb) =
              *(const f16x8*)&S[rowL * 136 + colb];
        }
        __syncthreads();
      }
    } else if (msegB == 0) {
      // fp8 dense path -> Q8 (512-byte rows)
      float* S = (float*)smem_raw;  // [32][132] floats
#pragma unroll
      for (int round = 0; round < 4; ++round) {
        if (wr == (round >> 1)) {
#pragma unroll
          for (int ii = 0; ii < 2; ++ii) {
#pragma unroll
            for (int j = 0; j < 4; ++j) {
              int colL = wc * 64 + j * 16 + cl;
              float bj = bias[n0 + colL];
#pragma unroll
              for (int rg = 0; rg < 4; ++rg) {
                int rowL = ii * 16 + rb + rg;
                S[rowL * 132 + colL] = acc[(round & 1) * 2 + ii][j][rg] + bj;
              }
            }
          }
        }
        __syncthreads();
#pragma unroll
        for (int it = 0; it < 2; ++it) {
          int id = it * 256 + tid;
          int rowL = id >> 4, ch = id & 15;
          int grow = m0 + round * 32 + rowL;
          int colb = ch * 8;
          float f[8];
          f32x4 lo = *(const f32x4*)&S[rowL * 132 + colb];
          f32x4 hi = *(const f32x4*)&S[rowL * 132 + colb + 4];
          f[0] = lo[0]; f[1] = lo[1]; f[2] = lo[2]; f[3] = lo[3];
          f[4] = hi[0]; f[5] = hi[1]; f[6] = hi[2]; f[7] = hi[3];
          uint2 pk = fp8_pack8(f);
          *(uint2*)(Q8 + (size_t)grow * 512 + cb + colb) = pk;
        }
        __syncthreads();
      }
    } else {
      // fp8 path -> KV8 interleaved [K 8B | V 8B] per 8-col group (1KB rows)
      float* S = (float*)smem_raw;  // [32][132] floats
      unsigned char* KV8 = (unsigned char*)KV;
      const int koff = (msegB == 2) ? 8 : 0;
#pragma unroll
      for (int round = 0; round < 4; ++round) {
        if (wr == (round >> 1)) {
#pragma unroll
          for (int ii = 0; ii < 2; ++ii) {
#pragma unroll
            for (int j = 0; j < 4; ++j) {
              int colL = wc * 64 + j * 16 + cl;
              float bj = bias[n0 + colL];
#pragma unroll
              for (int rg = 0; rg < 4; ++rg) {
                int rowL = ii * 16 + rb + rg;
                S[rowL * 132 + colL] = acc[(round & 1) * 2 + ii][j][rg] + bj;
              }
            }
          }
        }
        __syncthreads();
#pragma unroll
        for (int it = 0; it < 2; ++it) {
          int id = it * 256 + tid;
          int rowL = id >> 4, ch = id & 15;
          int grow = m0 + round * 32 + rowL;
          int colb = ch * 8;
          float f[8];
          f32x4 lo = *(const f32x4*)&S[rowL * 132 + colb];
          f32x4 hi = *(const f32x4*)&S[rowL * 132 + colb + 4];
          f[0] = lo[0]; f[1] = lo[1]; f[2] = lo[2]; f[3] = lo[3];
          f[4] = hi[0]; f[5] = hi[1]; f[6] = hi[2]; f[7] = hi[3];
          uint2 pk = fp8_pack8(f);
          *(uint2*)(KV8 + (size_t)grow * 1024 + ((cb + colb) >> 3) * 16 + koff) = pk;
        }
        __syncthreads();
      }
    }
  }
}

// ---------------- attention H=8 C=64: one WAVE per node, fp8 Q/KV ----------------
__global__ __launch_bounds__(256)
void attn_h8_kernel(const unsigned char* __restrict__ Q8,
                    const __half* __restrict__ S16,
                    const unsigned char* __restrict__ KV8,
                    const int* __restrict__ rowptr, const int* __restrict__ col,
                    __half* __restrict__ Hout, int N) {
  int n = blockIdx.x * 4 + (threadIdx.x >> 6);
  if (n >= N) return;
  int lane = threadIdx.x & 63;

  uint2 qw = *(const uint2*)(Q8 + (size_t)n * 512 + lane * 8);
  float qf[8];
  fp8x4_to_f32(qw.x, qf);
  fp8x4_to_f32(qw.y, qf + 4);

  int e0 = rowptr[n], e1 = rowptr[n + 1];
  float m = -INFINITY, l = 0.f;
  float o[8] = {};

  const uint4* KVL = (const uint4*)KV8;  // one row = 64 uint4 (lane-interleaved K|V)
  uint4 ea = {}, eb = {};
  int i = e0;
  if (i < e1)     ea = KVL[(size_t)col[i] * 64 + lane];
  if (i + 1 < e1) eb = KVL[(size_t)col[i + 1] * 64 + lane];

  while (i < e1) {
    int rem = e1 - i;
    uint4 ec = {}, ed = {};
    if (rem > 2) ec = KVL[(size_t)col[i + 2] * 64 + lane];
    if (rem > 3) ed = KVL[(size_t)col[i + 3] * 64 + lane];
    float ka[8], kb[8];
    fp8x4_to_f32(ea.x, ka); fp8x4_to_f32(ea.y, ka + 4);
    fp8x4_to_f32(eb.x, kb); fp8x4_to_f32(eb.y, kb + 4);
    float pa = 0.f, pb = 0.f;
#pragma unroll
    for (int j = 0; j < 8; ++j) { pa += ka[j] * qf[j]; pb += kb[j] * qf[j]; }
    pa += __shfl_xor(pa, 1, 64); pb += __shfl_xor(pb, 1, 64);
    pa += __shfl_xor(pa, 2, 64); pb += __shfl_xor(pb, 2, 64);
    pa += __shfl_xor(pa, 4, 64); pb += __shfl_xor(pb, 4, 64);
    float a0 = pa * 0.125f;
    float va[8];
    fp8x4_to_f32(ea.z, va); fp8x4_to_f32(ea.w, va + 4);
    if (rem > 1) {
      float vb[8];
      fp8x4_to_f32(eb.z, vb); fp8x4_to_f32(eb.w, vb + 4);
      float a1 = pb * 0.125f;
      float mn = fmaxf(m, fmaxf(a0, a1));
      float sc = __expf(m - mn);
      float ex0 = __expf(a0 - mn), ex1 = __expf(a1 - mn);
      l = l * sc + ex0 + ex1;
#pragma unroll
      for (int c = 0; c < 8; ++c)
        o[c] = o[c] * sc + ex0 * va[c] + ex1 * vb[c];
      m = mn;
    } else {
      float mn = fmaxf(m, a0);
      float sc = __expf(m - mn);
      float ex0 = __expf(a0 - mn);
      l = l * sc + ex0;
#pragma unroll
      for (int c = 0; c < 8; ++c) o[c] = o[c] * sc + ex0 * va[c];
      m = mn;
    }
    ea = ec; eb = ed;
    i += 2;
  }

  float inv = 1.f / (l + 1e-16f);
  f16x8 sv = __builtin_nontemporal_load((const f16x8*)(S16 + (size_t)n * 512 + lane * 8));
  f16x8 hv;
#pragma unroll
  for (int c = 0; c < 8; ++c) {
    float r = o[c] * inv + (float)sv[c];
    hv[c] = (_Float16)fmaxf(r, 0.f);
  }
  __builtin_nontemporal_store(hv, (f16x8*)(Hout + (size_t)n * 512 + lane * 8));
}

// ---------------- attention H=1 C=64: 8-lane group per node, fp16 KV ----------------
__global__ __launch_bounds__(256)
void attn_h1_kernel(const __half* __restrict__ QS, const __half* __restrict__ KV,
                    const int* __restrict__ rowptr, const int* __restrict__ col,
                    float* __restrict__ out, int N) {
  int n = (blockIdx.x * 256 + threadIdx.x) >> 3;
  if (n >= N) return;
  int gl = threadIdx.x & 7;
  size_t rbase = (size_t)n * 128 + gl * 8;

  f16x8 qv = __builtin_nontemporal_load((const f16x8*)(QS + rbase));
  float qf[8];
#pragma unroll
  for (int j = 0; j < 8; ++j) qf[j] = (float)qv[j];

  int e0 = rowptr[n], e1 = rowptr[n + 1];
  float m = -INFINITY, l = 0.f;
  float o[8] = {};

  f16x8 ka = {}, va = {}, kb = {}, vb = {};
  int i = e0;
  if (i < e1) {
    const __half* p = KV + (size_t)col[i] * 128 + gl * 8;
    ka = *(const f16x8*)p; va = *(const f16x8*)(p + 64);
  }
  if (i + 1 < e1) {
    const __half* p = KV + (size_t)col[i + 1] * 128 + gl * 8;
    kb = *(const f16x8*)p; vb = *(const f16x8*)(p + 64);
  }

  while (i < e1) {
    int rem = e1 - i;
    f16x8 kc = {}, vc = {}, kd = {}, vd = {};
    if (rem > 2) {
      const __half* p = KV + (size_t)col[i + 2] * 128 + gl * 8;
      kc = *(const f16x8*)p; vc = *(const f16x8*)(p + 64);
    }
    if (rem > 3) {
      const __half* p = KV + (size_t)col[i + 3] * 128 + gl * 8;
      kd = *(const f16x8*)p; vd = *(const f16x8*)(p + 64);
    }
    float pa = 0.f, pb = 0.f;
#pragma unroll
    for (int j = 0; j < 8; ++j) { pa += (float)ka[j] * qf[j]; pb += (float)kb[j] * qf[j]; }
    pa += __shfl_xor(pa, 1, 64); pb += __shfl_xor(pb, 1, 64);
    pa += __shfl_xor(pa, 2, 64); pb += __shfl_xor(pb, 2, 64);
    pa += __shfl_xor(pa, 4, 64); pb += __shfl_xor(pb, 4, 64);
    float a0 = pa * 0.125f;
    if (rem > 1) {
      float a1 = pb * 0.125f;
      float mn = fmaxf(m, fmaxf(a0, a1));
      float sc = __expf(m - mn);
      float ea = __expf(a0 - mn), eb = __expf(a1 - mn);
      l = l * sc + ea + eb;
#pragma unroll
      for (int c = 0; c < 8; ++c)
        o[c] = o[c] * sc + ea * (float)va[c] + eb * (float)vb[c];
      m = mn;
    } else {
      float mn = fmaxf(m, a0);
      float sc = __expf(m - mn);
      float ea = __expf(a0 - mn);
      l = l * sc + ea;
#pragma unroll
      for (int c = 0; c < 8; ++c) o[c] = o[c] * sc + ea * (float)va[c];
      m = mn;
    }
    ka = kc; va = vc; kb = kd; vb = vd;
    i += 2;
  }

  float inv = 1.f / (l + 1e-16f);
  f16x8 sv = __builtin_nontemporal_load((const f16x8*)(QS + rbase + 64));
  f32x4 r0, r1;
#pragma unroll
  for (int c = 0; c < 4; ++c) r0[c] = o[c] * inv + (float)sv[c];
#pragma unroll
  for (int c = 0; c < 4; ++c) r1[c] = o[c + 4] * inv + (float)sv[c + 4];
  float* op = out + (size_t)n * 64 + gl * 8;
  *(f32x4*)op = r0;
  *(f32x4*)(op + 4) = r1;
}

extern "C" void kernel_launch(void* const* d_in, const int* in_sizes, int n_in,
                              void* d_out, int out_size, void* d_ws, size_t ws_size,
                              hipStream_t stream) {
  const float* x = (const float*)d_in[0];
  const int* ei = (const int*)d_in[1];
  const int N = in_sizes[0] / 128;
  const int E = in_sizes[1] / 2;
  // pad M so mtiles is a multiple of 8 (XCD striping)
  const int Npad = ((N + 1023) / 1024) * 1024;
  const int mtiles = Npad / 128;
  const int* srcp = ei;
  const int* dstp = ei + E;

  const float* Wq0 = (const float*)d_in[2];  const float* bq0 = (const float*)d_in[3];
  const float* Wk0 = (const float*)d_in[4];  const float* bk0 = (const float*)d_in[5];
  const float* Wv0 = (const float*)d_in[6];  const float* bv0 = (const float*)d_in[7];
  const float* Ws0 = (const float*)d_in[8];  const float* bs0 = (const float*)d_in[9];
  const float* Wq1 = (const float*)d_in[10]; const float* bq1 = (const float*)d_in[11];
  const float* Wk1 = (const float*)d_in[12]; const float* bk1 = (const float*)d_in[13];
  const float* Wv1 = (const float*)d_in[14]; const float* bv1 = (const float*)d_in[15];
  const float* Ws1 = (const float*)d_in[16]; const float* bs1 = (const float*)d_in[17];
  const float* Wq2 = (const float*)d_in[18]; const float* bq2 = (const float*)d_in[19];
  const float* Wk2 = (const float*)d_in[20]; const float* bk2 = (const float*)d_in[21];
  const float* Wv2 = (const float*)d_in[22]; const float* bv2 = (const float*)d_in[23];
  const float* Ws2 = (const float*)d_in[24]; const float* bs2 = (const float*)d_in[25];

  // ---- workspace layout ----
  char* p = (char*)d_ws;
  __half* S16 = (__half*)p;              p += (size_t)Npad * 512 * 2;   // 51.4 MB (S; layer2 reuses as QS 128-half rows)
  unsigned char* Q8 = (unsigned char*)p; p += (size_t)Npad * 512;       // 25.7 MB
  __half* KV = (__half*)p;               p += (size_t)Npad * 1024;      // fp8 1KB rows; layer2 fp16 256B rows
  __half* H  = (__half*)p;               p += (size_t)Npad * 512 * 2;   // 51.4 MB
  __half* xh = (__half*)p;               p += (size_t)Npad * 128 * 2;   // 12.8 MB
  __half* Wt = (__half*)p;               p += (size_t)1441792 * 2;      // 2.88 MB
  float* bias_arena = (float*)p;         p += 4352 * 4;
  int* deg    = (int*)p;                 p += (size_t)N * 4;
  int* rowptr = (int*)p;                 p += (size_t)(N + 1) * 4;
  int* cursor = (int*)p;                 p += (size_t)(N + 1) * 4;
  int* colv   = (int*)p;                 p += (size_t)E * 4;
  int* bsum   = (int*)p;                 p += 256 * 4;
  size_t need = p - (char*)d_ws;
  if (ws_size < need) {
    fprintf(stderr, "kernel_launch: ws_size=%zu < need=%zu — aborting cleanly\n",
            ws_size, need);
    return;
  }

  const int nscan = (N + 255) / 256;

  // ---- prep ----
  transpose_all_kernel<<<dim3(16, 16, 12), 256, 0, stream>>>(
      Wq0, Wk0, Wv0, Ws0, Wq1, Wk1, Wv1, Ws1, Wq2, Wk2, Wv2, Ws2, Wt);
  bias_all_kernel<<<12, 256, 0, stream>>>(
      bq0, bk0, bv0, bs0, bq1, bk1, bv1, bs1, bq2, bk2, bv2, bs2, bias_arena);
  prep_x_kernel<<<(Npad * 16 + 255) / 256, 256, 0, stream>>>(x, xh, deg, H, N, Npad);

  // ---- CSR build ----
  degree_kernel<<<(E + 255) / 256, 256, 0, stream>>>(dstp, deg, E);
  scan_a_kernel<<<nscan, 256, 0, stream>>>(deg, rowptr, bsum, N);
  scan_b_kernel<<<1, 256, 0, stream>>>(bsum, nscan);
  scan_c_kernel<<<nscan, 256, 0, stream>>>(rowptr, cursor, bsum, N);
  scatter_kernel<<<(E + 255) / 256, 256, 0, stream>>>(srcp, dstp, cursor, colv, E);

  __half* Wt0 = Wt;
  __half* Wt1 = Wt + 262144;
  __half* Wt2 = Wt + 1310720;

  // ---- layer 0: K=128, D=2048 cols, n-tiles 16 ----
  gemm_mfma_kernel<0><<<mtiles * 16, 256, 0, stream>>>(
      xh, Wt0, bias_arena, S16, KV, Q8, S16);
  attn_h8_kernel<<<(N + 3) / 4, 256, 0, stream>>>(Q8, S16, (const unsigned char*)KV,
                                                  rowptr, colv, H, N);

  // ---- layer 1: K=512, D=2048 cols, n-tiles 16 ----
  gemm_mfma_kernel<1><<<mtiles * 16, 256, 0, stream>>>(
      H, Wt1, bias_arena + 2048, S16, KV, Q8, S16);
  attn_h8_kernel<<<(N + 3) / 4, 256, 0, stream>>>(Q8, S16, (const unsigned char*)KV,
                                                  rowptr, colv, H, N);

  // ---- layer 2: K=512, D=256 cols, n-tiles 2 (fp16 path, S16 reused as QS) ----
  gemm_mfma_kernel<2><<<mtiles * 2, 256, 0, stream>>>(
      H, Wt2, bias_arena + 4096, S16, KV, Q8, S16);
  attn_h1_kernel<<<(N + 31) / 32, 256, 0, stream>>>(S16, KV, rowptr, colv,
                                                    (float*)d_out, N);
}